// Round 8
// baseline (1523.877 us; speedup 1.0000x reference)
//
#include <hip/hip_runtime.h>
#include <hip/hip_bf16.h>

constexpr int cB = 32, cN = 64, cL = 64, cT = 10, cD = 256, cH = 512, cH3 = 1536;
constexpr int cBN = cB * cN;   // 2048
constexpr int cNP1 = cN + 1;   // 65: hidden tape, slot 0 = h0, slot n+1 = hs[:,n,:]
constexpr int SCAN_BLOCKS = 256;
constexpr int SCAN_LDS = (512 * 48 + 4 * 512 + 256 * 13) * 4;  // 119808 B

// ---------------- x[bn][d] = sum_l emb[sents[bn][l]][d] ----------------
__global__ void k_embed_x(const int* __restrict__ sents, const float* __restrict__ emb,
                          float* __restrict__ x) {
  __shared__ int idx[cL];
  int bn = blockIdx.x, t = threadIdx.x;
  if (t < cL) idx[t] = sents[bn * cL + t];
  __syncthreads();
  float acc = 0.f;
#pragma unroll 8
  for (int l = 0; l < cL; ++l) acc += emb[(long)idx[l] * cD + t];
  x[bn * cD + t] = acc;
}

// ---------------- tsum[b][d] = sum_t emb[titles[b][0][t]][d] ----------------
__global__ void k_title(const int* __restrict__ titles, const float* __restrict__ emb,
                        float* __restrict__ tsum) {
  __shared__ int idx[cT];
  int b = blockIdx.x, t = threadIdx.x;
  if (t < cT) idx[t] = titles[b * cN * cT + t];
  __syncthreads();
  float acc = 0.f;
#pragma unroll
  for (int i = 0; i < cT; ++i) acc += emb[(long)idx[i] * cD + t];
  tsum[b * cD + t] = acc;
}

// ---------------- h0 = tsum @ Wt + bt -> hse slot 0 ----------------
__global__ void k_h0(const float* __restrict__ tsum, const float* __restrict__ Wt,
                     const float* __restrict__ bt, float* __restrict__ hse) {
  int i = blockIdx.x * blockDim.x + threadIdx.x;  // B*H
  int b = i >> 9, hh = i & (cH - 1);
  const float* ts = tsum + b * cD;
  float acc = bt[hh];
  for (int k = 0; k < cD; ++k) acc += ts[k] * Wt[(long)k * cH + hh];
  hse[(long)b * cNP1 * cH + hh] = acc;
}

// ---------------- GI = X @ W_ih + b_ih ----------------
__global__ void k_gi(const float* __restrict__ x, const float* __restrict__ W_ih,
                     const float* __restrict__ b_ih, float* __restrict__ gi) {
  __shared__ float s[8 * cD];                      // 8 KB
  int cg = blockIdx.x;
  int row0 = blockIdx.y * 8;
  int t = threadIdx.x;
  float4* s4 = (float4*)s;
  const float4* x4 = (const float4*)(x + (long)row0 * cD);
#pragma unroll
  for (int i = t; i < 8 * (cD / 4); i += 256) s4[i] = x4[i];
  __syncthreads();
  int col = cg * 256 + t;
  float acc[8] = {0, 0, 0, 0, 0, 0, 0, 0};
#pragma unroll 2
  for (int k4 = 0; k4 < cD / 4; ++k4) {
    float4 a[8];
#pragma unroll
    for (int m = 0; m < 8; ++m) a[m] = s4[m * (cD / 4) + k4];
    const float* wp = W_ih + (long)(k4 * 4) * cH3 + col;
    float w0 = wp[0], w1 = wp[cH3], w2 = wp[2 * cH3], w3 = wp[3 * cH3];
#pragma unroll
    for (int m = 0; m < 8; ++m)
      acc[m] += a[m].x * w0 + a[m].y * w1 + a[m].z * w2 + a[m].w * w3;
  }
  float bb = b_ih[col];
#pragma unroll
  for (int m = 0; m < 8; ++m) gi[(long)(row0 + m) * cH3 + col] = acc[m] + bb;
}

// ---------------- init barrier counter ----------------
__global__ void k_init(unsigned* cnt) {
  if (threadIdx.x == 0) *cnt = 0u;
}

// ---------------- persistent GRU scan ----------------
// 256 blocks = bg(8: 4 batches) x cg(32: 16 cols).  1 block/CU (117 KB LDS).
// W_hh slice staged in LDS once; per step: h-stage, partial matmul, gates, grid barrier.
__global__ void __launch_bounds__(256, 1) k_scan(
    const float* __restrict__ gi, const float* __restrict__ W_hh,
    const float* __restrict__ b_hh, float* __restrict__ hse, unsigned* cnt) {
  extern __shared__ float sm[];
  float* wlds = sm;                   // [512][48]: col j = gate*16 + cl
  float* hsm = wlds + 512 * 48;       // [512][4] transposed: hsm[k*4+b]
  float* part = hsm + 4 * 512;        // [256][13]
  int bg = blockIdx.x >> 5;
  int cg = blockIdx.x & 31;
  int t = threadIdx.x;
  int hh0 = cg * 16;

  // stage W slice: wlds[k*48 + g*16 + cl] = W_hh[k][g*512 + hh0 + cl]
  for (int idx = t; idx < 512 * 48; idx += 256) {
    int k = idx / 48, j = idx - k * 48;
    int g = j >> 4, cl = j & 15;
    wlds[idx] = W_hh[(long)k * cH3 + g * cH + hh0 + cl];
  }

  int kp = t >> 4;          // 16 k-parts, k = kp + 16*i
  int b = (t >> 2) & 3;     // batch lane
  int c4 = t & 3;           // col quad
  const float* wthread = wlds + c4 * 4;

  for (int s = 0; s < cN; ++s) {
    // stage h (transposed): hsm[k*4+b] = hse[bg*4+b][s][k]
    for (int idx = t; idx < 2048; idx += 256) {
      int k = idx >> 2, bb = idx & 3;
      hsm[idx] = hse[((long)(bg * 4 + bb) * cNP1 + s) * cH + k];
    }
    __syncthreads();

    float ar[4] = {0, 0, 0, 0}, az[4] = {0, 0, 0, 0}, an[4] = {0, 0, 0, 0};
#pragma unroll 4
    for (int i = 0; i < 32; ++i) {
      int k = kp + (i << 4);
      float hv = hsm[(k << 2) | b];
      const float* wp = wthread + k * 48;
      float4 wr = *(const float4*)(wp);
      float4 wz = *(const float4*)(wp + 16);
      float4 wn = *(const float4*)(wp + 32);
      ar[0] += hv * wr.x; ar[1] += hv * wr.y; ar[2] += hv * wr.z; ar[3] += hv * wr.w;
      az[0] += hv * wz.x; az[1] += hv * wz.y; az[2] += hv * wz.z; az[3] += hv * wz.w;
      an[0] += hv * wn.x; an[1] += hv * wn.y; an[2] += hv * wn.z; an[3] += hv * wn.w;
    }
    float* pt = part + t * 13;
#pragma unroll
    for (int j = 0; j < 4; ++j) {
      pt[j] = ar[j];
      pt[4 + j] = az[j];
      pt[8 + j] = an[j];
    }
    __syncthreads();

    if (t < 64) {
      int b_l = t >> 4, cl = t & 15;
      int c4f = cl >> 2, jf = cl & 3;
      float sr = 0.f, sz = 0.f, sn = 0.f;
#pragma unroll
      for (int p = 0; p < 16; ++p) {
        const float* pp = part + (p * 16 + b_l * 4 + c4f) * 13;
        sr += pp[jf];
        sz += pp[4 + jf];
        sn += pp[8 + jf];
      }
      int bb = bg * 4 + b_l;
      int hh = hh0 + cl;
      long girow = ((long)bb * cN + s) * cH3;
      float R = sr + b_hh[hh];
      float Z = sz + b_hh[hh + cH];
      float Nn = sn + b_hh[hh + 2 * cH];
      float ir = gi[girow + hh];
      float iz = gi[girow + hh + cH];
      float in_ = gi[girow + hh + 2 * cH];
      float rr = 1.f / (1.f + __expf(-(ir + R)));
      float zz = 1.f / (1.f + __expf(-(iz + Z)));
      float nn = tanhf(in_ + rr * Nn);
      hse[((long)bb * cNP1 + s + 1) * cH + hh] =
          (1.f - zz) * nn + zz * hsm[hh * 4 + b_l];
    }

    if (s < cN - 1) {  // grid barrier: h tape is append-only, one barrier/step
      __syncthreads();
      if (t == 0) {
        __threadfence();  // make this block's h writes device-visible (cross-XCD)
        __hip_atomic_fetch_add(cnt, 1u, __ATOMIC_RELEASE, __HIP_MEMORY_SCOPE_AGENT);
        unsigned target = (unsigned)SCAN_BLOCKS * (unsigned)(s + 1);
        while (__hip_atomic_load(cnt, __ATOMIC_RELAXED, __HIP_MEMORY_SCOPE_AGENT) < target)
          __builtin_amdgcn_s_sleep(2);
        __threadfence();  // acquire: invalidate stale caches before reading others' h
      }
      __syncthreads();
    }
  }
}

// ---------------- q = hs @ W_att_in ----------------
__global__ void k_q(const float* __restrict__ hse, const float* __restrict__ W,
                    float* __restrict__ q) {
  __shared__ float s[8 * cH];                      // 16 KB
  int cg = blockIdx.x;
  int row0 = blockIdx.y * 8;
  int t = threadIdx.x;
  float4* s4 = (float4*)s;
#pragma unroll
  for (int i = t; i < 8 * 128; i += 256) {
    int m = i >> 7, k4 = i & 127;
    int bn = row0 + m;
    int b = bn >> 6, n = bn & 63;
    const float4* r4 = (const float4*)(hse + ((long)b * cNP1 + 1 + n) * cH);
    s4[m * 128 + k4] = r4[k4];
  }
  __syncthreads();
  int col = cg * 256 + t;
  float acc[8] = {0, 0, 0, 0, 0, 0, 0, 0};
#pragma unroll 2
  for (int k4 = 0; k4 < cH / 4; ++k4) {
    float4 a[8];
#pragma unroll
    for (int m = 0; m < 8; ++m) a[m] = s4[m * 128 + k4];
    const float* wp = W + (long)(k4 * 4) * cH + col;
    float w0 = wp[0], w1 = wp[cH], w2 = wp[2 * cH], w3 = wp[3 * cH];
#pragma unroll
    for (int m = 0; m < 8; ++m)
      acc[m] += a[m].x * w0 + a[m].y * w1 + a[m].z * w2 + a[m].w * w3;
  }
#pragma unroll
  for (int m = 0; m < 8; ++m) q[(long)(row0 + m) * cH + col] = acc[m];
}

// ---------------- causal attention: scores + softmax + context ----------------
__global__ void k_attn(const float* __restrict__ q, const float* __restrict__ hse,
                       float* __restrict__ c) {
  __shared__ float qs[cH];
  __shared__ float part[256];
  __shared__ float aw[cN];
  int bn = blockIdx.x;
  int b = bn >> 6, n = bn & 63;
  int t = threadIdx.x;
  qs[t] = q[(long)bn * cH + t];
  qs[t + 256] = q[(long)bn * cH + t + 256];
  __syncthreads();
  int k = t & 63;
  int p = t >> 6;  // 4 partials per key
  const float* hrow = hse + ((long)b * cNP1 + 1 + k) * cH + p * 128;
  float s = 0.f;
#pragma unroll 8
  for (int j = 0; j < 128; ++j) s += qs[p * 128 + j] * hrow[j];
  part[t] = s;
  __syncthreads();
  if (t < 64) {
    float sc = part[t] + part[t + 64] + part[t + 128] + part[t + 192];
    if (t > n) sc = -1e30f;  // ref adds log(1e-45) ~ -103.6 -> exp underflows to 0
    float m = sc;
#pragma unroll
    for (int off = 32; off; off >>= 1) m = fmaxf(m, __shfl_xor(m, off));
    float e = __expf(sc - m);
    float sum = e;
#pragma unroll
    for (int off = 32; off; off >>= 1) sum += __shfl_xor(sum, off);
    aw[t] = e / sum;
  }
  __syncthreads();
  float c0 = 0.f, c1 = 0.f;
  for (int kk = 0; kk < cN; ++kk) {
    float a = aw[kk];
    const float* hr = hse + ((long)b * cNP1 + 1 + kk) * cH;
    c0 += a * hr[t];
    c1 += a * hr[t + 256];
  }
  c[(long)bn * cH + t] = c0;
  c[(long)bn * cH + t + 256] = c1;
}

// ---------------- out partials over k-halves ----------------
__global__ void k_outp(const float* __restrict__ c, const float* __restrict__ hse,
                       const float* __restrict__ W, float* __restrict__ pko) {
  __shared__ float s[8 * cH];                      // 16 KB
  int cg = blockIdx.x;
  int row0 = blockIdx.y * 8;
  int kp = blockIdx.z;
  int t = threadIdx.x;
  float4* s4 = (float4*)s;
#pragma unroll
  for (int i = t; i < 8 * 128; i += 256) {
    int m = i >> 7, k4 = i & 127;
    int bn = row0 + m;
    int b = bn >> 6, n = bn & 63;
    const float4* src = (kp == 0) ? (const float4*)(c + (long)bn * cH)
                                  : (const float4*)(hse + ((long)b * cNP1 + 1 + n) * cH);
    s4[m * 128 + k4] = src[k4];
  }
  __syncthreads();
  int col = cg * 256 + t;
  float acc[8] = {0, 0, 0, 0, 0, 0, 0, 0};
#pragma unroll 2
  for (int k4 = 0; k4 < 128; ++k4) {
    float4 a[8];
#pragma unroll
    for (int m = 0; m < 8; ++m) a[m] = s4[m * 128 + k4];
    const float* wp = W + (long)(kp * cH + k4 * 4) * cH + col;
    float w0 = wp[0], w1 = wp[cH], w2 = wp[2 * cH], w3 = wp[3 * cH];
#pragma unroll
    for (int m = 0; m < 8; ++m)
      acc[m] += a[m].x * w0 + a[m].y * w1 + a[m].z * w2 + a[m].w * w3;
  }
#pragma unroll
  for (int m = 0; m < 8; ++m)
    pko[((long)kp * cBN + row0 + m) * cH + col] = acc[m];
}

// ---------------- out = tanh(p0 + p1 + bias) ----------------
__global__ void k_outr(const float* __restrict__ pko, const float* __restrict__ bias,
                       float* __restrict__ out) {
  int bn = blockIdx.x, col = threadIdx.x;  // 512 threads
  long i = (long)bn * cH + col;
  out[i] = tanhf(pko[i] + pko[(long)cBN * cH + i] + bias[col]);
}

extern "C" void kernel_launch(void* const* d_in, const int* in_sizes, int n_in,
                              void* d_out, int out_size, void* d_ws, size_t ws_size,
                              hipStream_t stream) {
  const int* sents = (const int*)d_in[0];
  const int* titles = (const int*)d_in[1];
  const float* emb = (const float*)d_in[2];
  const float* Wt = (const float*)d_in[3];
  const float* bt = (const float*)d_in[4];
  const float* W_ih = (const float*)d_in[5];
  const float* W_hh = (const float*)d_in[6];
  const float* b_ih = (const float*)d_in[7];
  const float* b_hh = (const float*)d_in[8];
  const float* W_att_in = (const float*)d_in[9];
  const float* W_att_out = (const float*)d_in[10];
  const float* b_att_out = (const float*)d_in[11];
  float* out = (float*)d_out;

  float* ws = (float*)d_ws;
  float* x = ws;                                   // BN*D
  float* tsum = x + (long)cBN * cD;                // B*D
  float* gi = tsum + (long)cB * cD;                // BN*3H (dead after scan)
  float* hse = gi + (long)cBN * cH3;               // B*65*H
  float* q = hse + (long)cB * cNP1 * cH;           // BN*H
  float* c = q + (long)cBN * cH;                   // BN*H
  unsigned* cnt = (unsigned*)(c + (long)cBN * cH); // barrier counter
  float* pko = gi;                                 // partials alias dead gi

  (void)hipFuncSetAttribute((const void*)k_scan,
                            hipFuncAttributeMaxDynamicSharedMemorySize, SCAN_LDS);

  k_init<<<1, 64, 0, stream>>>(cnt);
  k_embed_x<<<cBN, 256, 0, stream>>>(sents, emb, x);
  k_title<<<cB, 256, 0, stream>>>(titles, emb, tsum);
  k_h0<<<(cB * cH) / 256, 256, 0, stream>>>(tsum, Wt, bt, hse);
  k_gi<<<dim3(6, cBN / 8), 256, 0, stream>>>(x, W_ih, b_ih, gi);
  k_scan<<<SCAN_BLOCKS, 256, SCAN_LDS, stream>>>(gi, W_hh, b_hh, hse, cnt);
  k_q<<<dim3(2, cBN / 8), 256, 0, stream>>>(hse, W_att_in, q);
  k_attn<<<cBN, 256, 0, stream>>>(q, hse, c);
  k_outp<<<dim3(2, cBN / 8, 2), 256, 0, stream>>>(c, hse, W_att_out, pko);
  k_outr<<<cBN, 512, 0, stream>>>(pko, b_att_out, out);
}

// Round 9
// 686.806 us; speedup vs baseline: 2.2188x; 2.2188x over previous
//
#include <hip/hip_runtime.h>
#include <hip/hip_bf16.h>

constexpr int cB = 32, cN = 64, cL = 64, cT = 10, cD = 256, cH = 512, cH3 = 1536;
constexpr int cBN = cB * cN;   // 2048
constexpr int cNP1 = cN + 1;   // 65: hidden tape, slot 0 = h0, slot n+1 = hs[:,n,:]

// ---------------- x[bn][d] = sum_l emb[sents[bn][l]][d] ----------------
__global__ void k_embed_x(const int* __restrict__ sents, const float* __restrict__ emb,
                          float* __restrict__ x) {
  __shared__ int idx[cL];
  int bn = blockIdx.x, t = threadIdx.x;
  if (t < cL) idx[t] = sents[bn * cL + t];
  __syncthreads();
  float acc = 0.f;
#pragma unroll 8
  for (int l = 0; l < cL; ++l) acc += emb[(long)idx[l] * cD + t];
  x[bn * cD + t] = acc;
}

// ---------------- tsum[b][d] = sum_t emb[titles[b][0][t]][d] ----------------
__global__ void k_title(const int* __restrict__ titles, const float* __restrict__ emb,
                        float* __restrict__ tsum) {
  __shared__ int idx[cT];
  int b = blockIdx.x, t = threadIdx.x;
  if (t < cT) idx[t] = titles[b * cN * cT + t];
  __syncthreads();
  float acc = 0.f;
#pragma unroll
  for (int i = 0; i < cT; ++i) acc += emb[(long)idx[i] * cD + t];
  tsum[b * cD + t] = acc;
}

// ---------------- h0 = tsum @ Wt + bt -> hse slot 0 ----------------
__global__ void k_h0(const float* __restrict__ tsum, const float* __restrict__ Wt,
                     const float* __restrict__ bt, float* __restrict__ hse) {
  int i = blockIdx.x * blockDim.x + threadIdx.x;  // B*H
  int b = i >> 9, hh = i & (cH - 1);
  const float* ts = tsum + b * cD;
  float acc = bt[hh];
  for (int k = 0; k < cD; ++k) acc += ts[k] * Wt[(long)k * cH + hh];
  hse[(long)b * cNP1 * cH + hh] = acc;
}

// ---------------- GI = X @ W_ih + b_ih ----------------
// grid (3 col-groups, 256 row-groups); block 128; C=4 cols/thread, M=8 rows/block
__global__ void k_gi(const float* __restrict__ x, const float* __restrict__ W_ih,
                     const float* __restrict__ b_ih, float* __restrict__ gi) {
  __shared__ float4 s4[8 * 64];                    // 8 rows x 256 k  (8 KB)
  int cg = blockIdx.x;
  int row0 = blockIdx.y * 8;
  int t = threadIdx.x;
  const float4* x4 = (const float4*)(x + (long)row0 * cD);
#pragma unroll
  for (int i = t; i < 8 * 64; i += 128) s4[i] = x4[i];  // rows contiguous
  __syncthreads();
  int col0 = cg * 512 + t * 4;
  float4 acc[8];
#pragma unroll
  for (int m = 0; m < 8; ++m) acc[m] = make_float4(0.f, 0.f, 0.f, 0.f);
#pragma unroll 2
  for (int k4 = 0; k4 < 64; ++k4) {
    float4 a[8];
#pragma unroll
    for (int m = 0; m < 8; ++m) a[m] = s4[m * 64 + k4];
#pragma unroll
    for (int j = 0; j < 4; ++j) {
      float4 w = *(const float4*)(W_ih + (long)(k4 * 4 + j) * cH3 + col0);
#pragma unroll
      for (int m = 0; m < 8; ++m) {
        float av = (j == 0) ? a[m].x : (j == 1) ? a[m].y : (j == 2) ? a[m].z : a[m].w;
        acc[m].x += av * w.x; acc[m].y += av * w.y;
        acc[m].z += av * w.z; acc[m].w += av * w.w;
      }
    }
  }
  float4 bb = *(const float4*)(b_ih + col0);
#pragma unroll
  for (int m = 0; m < 8; ++m) {
    float4 o = make_float4(acc[m].x + bb.x, acc[m].y + bb.y, acc[m].z + bb.z, acc[m].w + bb.w);
    *(float4*)(gi + (long)(row0 + m) * cH3 + col0) = o;
  }
}

// ---------------- one GRU step (round-7 proven version) ----------------
// grid 512 = bg(16: 2 batches) x cg(32: 16 cols/gate); block 256
__global__ void k_gru_step(const float* __restrict__ gi, const float* __restrict__ W_hh,
                           const float* __restrict__ b_hh, float* __restrict__ hse, int step) {
  __shared__ float hsm[2][cH];
  __shared__ float part[256][13];   // stride 13: conflict-free partial writes
  int cg = blockIdx.x & 31;
  int bg = blockIdx.x >> 5;
  int t = threadIdx.x;
  {  // stage 2 hidden rows (4 KB): 256 threads x 1 float4
    int m = t >> 7, k4 = t & 127;
    const float4* r4 = (const float4*)(hse + ((long)(bg * 2 + m) * cNP1 + step) * cH);
    ((float4*)&hsm[m][0])[k4] = r4[k4];
  }
  __syncthreads();
  int c4 = t & 3, b = (t >> 2) & 1, kp = t >> 3;
  int col0 = cg * 16 + c4 * 4;
  float ar[4] = {0, 0, 0, 0}, az[4] = {0, 0, 0, 0}, an[4] = {0, 0, 0, 0};
  int k0 = kp * 16;
#pragma unroll
  for (int k = k0; k < k0 + 16; ++k) {
    float hv = hsm[b][k];
    const float* wp = W_hh + (long)k * cH3 + col0;
    float4 wr = *(const float4*)(wp);
    float4 wz = *(const float4*)(wp + cH);
    float4 wn = *(const float4*)(wp + 2 * cH);
    ar[0] += hv * wr.x; ar[1] += hv * wr.y; ar[2] += hv * wr.z; ar[3] += hv * wr.w;
    az[0] += hv * wz.x; az[1] += hv * wz.y; az[2] += hv * wz.z; az[3] += hv * wz.w;
    an[0] += hv * wn.x; an[1] += hv * wn.y; an[2] += hv * wn.z; an[3] += hv * wn.w;
  }
#pragma unroll
  for (int j = 0; j < 4; ++j) {
    part[t][j] = ar[j];
    part[t][4 + j] = az[j];
    part[t][8 + j] = an[j];
  }
  __syncthreads();
  if (t < 32) {  // 32 outputs: b_l in [0,2), cl in [0,16)
    int b_l = t >> 4, cl = t & 15;
    int c4f = cl >> 2, jf = cl & 3;
    float sr = 0.f, sz = 0.f, sn = 0.f;
#pragma unroll
    for (int p = 0; p < 32; ++p) {
      const float* pp = part[p * 8 + b_l * 4 + c4f];
      sr += pp[jf];
      sz += pp[4 + jf];
      sn += pp[8 + jf];
    }
    int bb = bg * 2 + b_l;
    int hh = cg * 16 + cl;
    long girow = ((long)bb * cN + step) * cH3;
    float R = sr + b_hh[hh];
    float Z = sz + b_hh[hh + cH];
    float Nn = sn + b_hh[hh + 2 * cH];
    float ir = gi[girow + hh];
    float iz = gi[girow + hh + cH];
    float in_ = gi[girow + hh + 2 * cH];
    float rr = 1.f / (1.f + __expf(-(ir + R)));
    float zz = 1.f / (1.f + __expf(-(iz + Z)));
    float nn = tanhf(in_ + rr * Nn);
    hse[((long)bb * cNP1 + step + 1) * cH + hh] = (1.f - zz) * nn + zz * hsm[b_l][hh];
  }
}

// ---------------- q = hs @ W_att_in ----------------
// grid (256 row-groups); block 128; C=4, M=8
__global__ void k_q(const float* __restrict__ hse, const float* __restrict__ W,
                    float* __restrict__ q) {
  __shared__ float4 s4[8 * 128];                   // 16 KB
  int row0 = blockIdx.x * 8;
  int t = threadIdx.x;
#pragma unroll
  for (int i = t; i < 8 * 128; i += 128) {
    int m = i >> 7, k4 = i & 127;
    int bn = row0 + m;
    int b = bn >> 6, n = bn & 63;
    s4[i] = ((const float4*)(hse + ((long)b * cNP1 + 1 + n) * cH))[k4];
  }
  __syncthreads();
  int col0 = t * 4;
  float4 acc[8];
#pragma unroll
  for (int m = 0; m < 8; ++m) acc[m] = make_float4(0.f, 0.f, 0.f, 0.f);
#pragma unroll 2
  for (int k4 = 0; k4 < 128; ++k4) {
    float4 a[8];
#pragma unroll
    for (int m = 0; m < 8; ++m) a[m] = s4[m * 128 + k4];
#pragma unroll
    for (int j = 0; j < 4; ++j) {
      float4 w = *(const float4*)(W + (long)(k4 * 4 + j) * cH + col0);
#pragma unroll
      for (int m = 0; m < 8; ++m) {
        float av = (j == 0) ? a[m].x : (j == 1) ? a[m].y : (j == 2) ? a[m].z : a[m].w;
        acc[m].x += av * w.x; acc[m].y += av * w.y;
        acc[m].z += av * w.z; acc[m].w += av * w.w;
      }
    }
  }
#pragma unroll
  for (int m = 0; m < 8; ++m)
    *(float4*)(q + (long)(row0 + m) * cH + col0) = acc[m];
}

// ---------------- causal attention: scores + softmax + context ----------------
__global__ void k_attn(const float* __restrict__ q, const float* __restrict__ hse,
                       float* __restrict__ c) {
  __shared__ float qs[cH];
  __shared__ float part[256];
  __shared__ float aw[cN];
  int bn = blockIdx.x;
  int b = bn >> 6, n = bn & 63;
  int t = threadIdx.x;
  qs[t] = q[(long)bn * cH + t];
  qs[t + 256] = q[(long)bn * cH + t + 256];
  __syncthreads();
  int k = t & 63;
  int p = t >> 6;  // 4 partials per key
  const float* hrow = hse + ((long)b * cNP1 + 1 + k) * cH + p * 128;
  float s = 0.f;
#pragma unroll 8
  for (int j = 0; j < 128; ++j) s += qs[p * 128 + j] * hrow[j];
  part[t] = s;
  __syncthreads();
  if (t < 64) {
    float sc = part[t] + part[t + 64] + part[t + 128] + part[t + 192];
    if (t > n) sc = -1e30f;  // ref adds log(1e-45) ~ -103.6 -> exp underflows to 0
    float m = sc;
#pragma unroll
    for (int off = 32; off; off >>= 1) m = fmaxf(m, __shfl_xor(m, off));
    float e = __expf(sc - m);
    float sum = e;
#pragma unroll
    for (int off = 32; off; off >>= 1) sum += __shfl_xor(sum, off);
    aw[t] = e / sum;
  }
  __syncthreads();
  float c0 = 0.f, c1 = 0.f;
  for (int kk = 0; kk < cN; ++kk) {
    float a = aw[kk];
    const float* hr = hse + ((long)b * cNP1 + 1 + kk) * cH;
    c0 += a * hr[t];
    c1 += a * hr[t + 256];
  }
  c[(long)bn * cH + t] = c0;
  c[(long)bn * cH + t + 256] = c1;
}

// ---------------- out partials over k-halves ----------------
// grid (256 row-groups, 2 kp); block 128; C=4, M=8
__global__ void k_outp(const float* __restrict__ c, const float* __restrict__ hse,
                       const float* __restrict__ W, float* __restrict__ pko) {
  __shared__ float4 s4[8 * 128];                   // 16 KB (half of concat per kp)
  int row0 = blockIdx.x * 8;
  int kp = blockIdx.y;
  int t = threadIdx.x;
#pragma unroll
  for (int i = t; i < 8 * 128; i += 128) {
    int m = i >> 7, k4 = i & 127;
    int bn = row0 + m;
    int b = bn >> 6, n = bn & 63;
    const float4* src = (kp == 0) ? (const float4*)(c + (long)bn * cH)
                                  : (const float4*)(hse + ((long)b * cNP1 + 1 + n) * cH);
    s4[i] = src[k4];
  }
  __syncthreads();
  int col0 = t * 4;
  float4 acc[8];
#pragma unroll
  for (int m = 0; m < 8; ++m) acc[m] = make_float4(0.f, 0.f, 0.f, 0.f);
#pragma unroll 2
  for (int k4 = 0; k4 < 128; ++k4) {
    float4 a[8];
#pragma unroll
    for (int m = 0; m < 8; ++m) a[m] = s4[m * 128 + k4];
#pragma unroll
    for (int j = 0; j < 4; ++j) {
      float4 w = *(const float4*)(W + (long)(kp * cH + k4 * 4 + j) * cH + col0);
#pragma unroll
      for (int m = 0; m < 8; ++m) {
        float av = (j == 0) ? a[m].x : (j == 1) ? a[m].y : (j == 2) ? a[m].z : a[m].w;
        acc[m].x += av * w.x; acc[m].y += av * w.y;
        acc[m].z += av * w.z; acc[m].w += av * w.w;
      }
    }
  }
#pragma unroll
  for (int m = 0; m < 8; ++m)
    *(float4*)(pko + ((long)kp * cBN + row0 + m) * cH + col0) = acc[m];
}

// ---------------- out = tanh(p0 + p1 + bias) ----------------
__global__ void k_outr(const float* __restrict__ pko, const float* __restrict__ bias,
                       float* __restrict__ out) {
  int bn = blockIdx.x, col = threadIdx.x;  // 512 threads
  long i = (long)bn * cH + col;
  out[i] = tanhf(pko[i] + pko[(long)cBN * cH + i] + bias[col]);
}

extern "C" void kernel_launch(void* const* d_in, const int* in_sizes, int n_in,
                              void* d_out, int out_size, void* d_ws, size_t ws_size,
                              hipStream_t stream) {
  const int* sents = (const int*)d_in[0];
  const int* titles = (const int*)d_in[1];
  const float* emb = (const float*)d_in[2];
  const float* Wt = (const float*)d_in[3];
  const float* bt = (const float*)d_in[4];
  const float* W_ih = (const float*)d_in[5];
  const float* W_hh = (const float*)d_in[6];
  const float* b_ih = (const float*)d_in[7];
  const float* b_hh = (const float*)d_in[8];
  const float* W_att_in = (const float*)d_in[9];
  const float* W_att_out = (const float*)d_in[10];
  const float* b_att_out = (const float*)d_in[11];
  float* out = (float*)d_out;

  float* ws = (float*)d_ws;
  float* x = ws;                                   // BN*D
  float* tsum = x + (long)cBN * cD;                // B*D
  float* gi = tsum + (long)cB * cD;                // BN*3H (dead after scan)
  float* hse = gi + (long)cBN * cH3;               // B*65*H
  float* q = hse + (long)cB * cNP1 * cH;           // BN*H
  float* c = q + (long)cBN * cH;                   // BN*H
  float* pko = gi;                                 // partials alias dead gi

  k_embed_x<<<cBN, 256, 0, stream>>>(sents, emb, x);
  k_title<<<cB, 256, 0, stream>>>(titles, emb, tsum);
  k_h0<<<(cB * cH) / 256, 256, 0, stream>>>(tsum, Wt, bt, hse);
  k_gi<<<dim3(3, cBN / 8), 128, 0, stream>>>(x, W_ih, b_ih, gi);
  for (int step = 0; step < cN; ++step)
    k_gru_step<<<512, 256, 0, stream>>>(gi, W_hh, b_hh, hse, step);
  k_q<<<cBN / 8, 128, 0, stream>>>(hse, W_att_in, q);
  k_attn<<<cBN, 256, 0, stream>>>(q, hse, c);
  k_outp<<<dim3(cBN / 8, 2), 128, 0, stream>>>(c, hse, W_att_out, pko);
  k_outr<<<cBN, 512, 0, stream>>>(pko, b_att_out, out);
}